// Round 11
// baseline (1149.355 us; speedup 1.0000x reference)
//
#include <hip/hip_runtime.h>

#define T_SEQ 769
#define N_SENT 768
#define E_IN 256
#define HID 128
#define G4 512
#define F_DIM 128

typedef _Float16 h2t __attribute__((ext_vector_type(2)));

#if __has_builtin(__builtin_amdgcn_fdot2)
#define FDOT2(a, b, c) __builtin_amdgcn_fdot2((a), (b), (c), false)
#else
#define FDOT2(a, b, c) fmaf((float)(a).x, (float)(b).x, fmaf((float)(a).y, (float)(b).y, (c)))
#endif

#if __has_builtin(__builtin_amdgcn_rcpf)
#define RCPF(x) __builtin_amdgcn_rcpf(x)
#else
#define RCPF(x) (1.0f / (x))
#endif

#if __has_builtin(__builtin_amdgcn_exp2f)
#define EXP2F(x) __builtin_amdgcn_exp2f(x)
#else
#define EXP2F(x) __builtin_exp2f(x)
#endif

// LDS-only barrier: waits lgkmcnt(0) then s_barrier; vmcnt (async global->LDS
// copies) stays in flight across it.
#define LDS_BARRIER() asm volatile("s_waitcnt lgkmcnt(0)\n\ts_barrier" ::: "memory")

#define L2E 1.4426950408889634f

// async global->LDS copy, 16B per lane: LDS dest = lbase (wave-uniform) + lane*16
__device__ __forceinline__ void async_g2l(const float* g, float* lbase) {
    __builtin_amdgcn_global_load_lds(
        (const __attribute__((address_space(1))) void*)g,
        (__attribute__((address_space(3))) void*)lbase, 16, 0, 0);
}

// DPP quad_perm helpers (VALU pipe; dpp_ctrl must be immediate -> template).
template <int CODE>
__device__ __forceinline__ float dpp_qperm(float x) {
    int v = __builtin_amdgcn_update_dpp(0, __builtin_bit_cast(int, x), CODE, 0xF, 0xF, true);
    return __builtin_bit_cast(float, v);
}
#define QP_XOR1 0xB1  // [1,0,3,2]
#define QP_XOR2 0x4E  // [2,3,0,1]
#define QP_B0   0x00
#define QP_B1   0x55
#define QP_B2   0xAA
#define QP_B3   0xFF

__device__ __forceinline__ float tanh_f(float x) {
    return 1.0f - 2.0f / (1.0f + __expf(2.0f * x));
}
__device__ __forceinline__ h2t u2h(unsigned u) { return __builtin_bit_cast(h2t, u); }

// x = concat(sentence (768x256), root (1x256))
__global__ void build_x(const float* __restrict__ sent, const float* __restrict__ root,
                        float* __restrict__ x) {
    int row = blockIdx.x;
    int c = threadIdx.x;
    x[row * E_IN + c] = (row < N_SENT) ? sent[row * E_IN + c] : root[c];
}

// C[m,n] = sum_k A[ar(m),k] * B[n,k] + b0[n] + b1[n]
__global__ __launch_bounds__(256) void gemm_nt(
    const float* __restrict__ A, int lda, int M, int revA,
    const float* __restrict__ B, int ldb,
    const float* __restrict__ b0, const float* __restrict__ b1,
    float* __restrict__ C, int ldc, int K)
{
    __shared__ __align__(16) float As[16][68];
    __shared__ __align__(16) float Bs[16][68];
    int tid = threadIdx.x;
    int tx = tid & 15, ty = tid >> 4;
    int m0 = blockIdx.x * 64, n0 = blockIdx.y * 64;
    float acc[4][4] = {};
    int lrow = tid >> 2;
    int lk = (tid & 3) << 2;

    for (int k0 = 0; k0 < K; k0 += 16) {
        int m = m0 + lrow;
        float4 av = make_float4(0.f, 0.f, 0.f, 0.f);
        if (m < M) {
            int ar = revA ? (M - 1 - m) : m;
            av = *(const float4*)(A + (size_t)ar * lda + k0 + lk);
        }
        As[lk + 0][lrow] = av.x; As[lk + 1][lrow] = av.y;
        As[lk + 2][lrow] = av.z; As[lk + 3][lrow] = av.w;
        float4 bv = *(const float4*)(B + (size_t)(n0 + lrow) * ldb + k0 + lk);
        Bs[lk + 0][lrow] = bv.x; Bs[lk + 1][lrow] = bv.y;
        Bs[lk + 2][lrow] = bv.z; Bs[lk + 3][lrow] = bv.w;
        __syncthreads();
        #pragma unroll
        for (int k = 0; k < 16; ++k) {
            float4 a4 = *(const float4*)&As[k][ty * 4];
            float4 b4 = *(const float4*)&Bs[k][tx * 4];
            float aa[4] = {a4.x, a4.y, a4.z, a4.w};
            float bb[4] = {b4.x, b4.y, b4.z, b4.w};
            #pragma unroll
            for (int i = 0; i < 4; ++i)
                #pragma unroll
                for (int j = 0; j < 4; ++j)
                    acc[i][j] = fmaf(aa[i], bb[j], acc[i][j]);
        }
        __syncthreads();
    }
    float bias[4];
    #pragma unroll
    for (int j = 0; j < 4; ++j) {
        int n = n0 + tx * 4 + j;
        bias[j] = (b0 ? b0[n] : 0.f) + (b1 ? b1[n] : 0.f);
    }
    #pragma unroll
    for (int i = 0; i < 4; ++i) {
        int m = m0 + ty * 4 + i;
        if (m < M) {
            #pragma unroll
            for (int j = 0; j < 4; ++j)
                C[(size_t)m * ldc + n0 + tx * 4 + j] = acc[i][j] + bias[j];
        }
    }
}

// One BiLSTM layer. grid = 2 (dir), block = 512 (8 waves).
// R10 compute structure (quad K-split, DPP transpose-reduce, per-lane gate
// activation) + R11 memory decoupling:
//  - pre staged global->LDS in 8-step/16KB chunks via global_load_lds,
//    triple-buffered; one manual s_waitcnt vmcnt(2) per chunk boundary.
//  - L writes staged in LDS (16-deep), flushed as coalesced 512B stores by
//    each wave once per 8 steps.
// The per-step loop has ZERO global memory ops -> the lgkm-only barrier no
// longer serializes HBM latency into each step.
__global__ __launch_bounds__(512)
__attribute__((amdgpu_waves_per_eu(2, 2)))
void lstm_layer(
    const float* __restrict__ pre,
    const float* __restrict__ Whh,
    float* __restrict__ L)
{
    const int d = blockIdx.x;
    const int t = threadIdx.x;
    const int wv_id = t >> 6;
    const int l = t & 63;
    const int usub = l >> 2;
    const int q = l & 3;
    const int u = wv_id * 16 + usub;

    __shared__ __align__(16) float pre_lds[3 * 8 * G4];      // 48 KB, 3 chunk bufs
    __shared__ __align__(16) float Lstage[16 * HID];         // 8 KB, 16-deep h stage
    __shared__ __align__(16) unsigned short hb[2][HID];      // h f16, dbuf

    const bool q1 = (q & 1) != 0;
    const bool q2 = (q & 2) != 0;
    const float Aa = (q == 2) ? 2.0f : 1.0f;
    const float Bb = (q == 2) ? (-2.0f * L2E) : (-L2E);
    const float Cc = (q == 2) ? -1.0f : 0.0f;

    // weights: gate g, unit u, K in [q*32, q*32+32) as 16 half2 -> 64 VGPRs
    h2t w[4][16];
    #pragma unroll
    for (int g = 0; g < 4; ++g) {
        const float* wr = Whh + ((size_t)d * G4 + g * HID + u) * HID + q * 32;
        #pragma unroll
        for (int k = 0; k < 16; ++k) {
            float2 v = *(const float2*)(wr + 2 * k);
            h2t p2v = {(_Float16)v.x, (_Float16)v.y};
            w[g][k] = p2v;
        }
    }

    if (t < HID) { hb[0][t] = 0; hb[1][t] = 0; }

    const float* pd = pre + (size_t)d * T_SEQ * G4;
    // issue chunks 0 and 1 (each: 8 steps x 512 floats; wave w covers 512 floats/instr x2)
    {
        const float* g0 = pd + wv_id * 512 + (l << 2);
        float* l0 = &pre_lds[0 * 4096 + wv_id * 512];
        async_g2l(g0, l0);
        async_g2l(g0 + 256, l0 + 256);
        const float* g1 = pd + 4096 + wv_id * 512 + (l << 2);
        float* l1 = &pre_lds[1 * 4096 + wv_id * 512];
        async_g2l(g1, l1);
        async_g2l(g1 + 256, l1 + 256);
    }
    float c = 0.f;
    __syncthreads();  // one-time full drain: chunk0(+1) ready, hb visible

    for (int s = 0; s < T_SEQ; ++s) {
        const int cs = s >> 3;
        const int so = s & 7;
        const int buf = cs % 3;

        // at chunk start: issue async load of chunk cs+2 into the free buffer
        if (so == 0 && cs + 2 <= (T_SEQ - 1) / 8) {
            const int c2 = cs + 2;
            const float* g = pd + (size_t)c2 * 4096 + wv_id * 512 + (l << 2);
            float* lb = &pre_lds[(c2 % 3) * 4096 + wv_id * 512];
            async_g2l(g, lb);
            async_g2l(g + 256, lb + 256);
        }

        float p = pre_lds[buf * 4096 + so * G4 + q * HID + u];

        const uint4* hp = (const uint4*)&hb[s & 1][q * 32];
        float a0 = 0.f, a1 = 0.f, a2 = 0.f, a3 = 0.f;
        #pragma unroll
        for (int k = 0; k < 4; ++k) {
            uint4 hv = hp[k];
            a0 = FDOT2(w[0][k * 4 + 0], u2h(hv.x), a0);
            a1 = FDOT2(w[1][k * 4 + 0], u2h(hv.x), a1);
            a2 = FDOT2(w[2][k * 4 + 0], u2h(hv.x), a2);
            a3 = FDOT2(w[3][k * 4 + 0], u2h(hv.x), a3);
            a0 = FDOT2(w[0][k * 4 + 1], u2h(hv.y), a0);
            a1 = FDOT2(w[1][k * 4 + 1], u2h(hv.y), a1);
            a2 = FDOT2(w[2][k * 4 + 1], u2h(hv.y), a2);
            a3 = FDOT2(w[3][k * 4 + 1], u2h(hv.y), a3);
            a0 = FDOT2(w[0][k * 4 + 2], u2h(hv.z), a0);
            a1 = FDOT2(w[1][k * 4 + 2], u2h(hv.z), a1);
            a2 = FDOT2(w[2][k * 4 + 2], u2h(hv.z), a2);
            a3 = FDOT2(w[3][k * 4 + 2], u2h(hv.z), a3);
            a0 = FDOT2(w[0][k * 4 + 3], u2h(hv.w), a0);
            a1 = FDOT2(w[1][k * 4 + 3], u2h(hv.w), a1);
            a2 = FDOT2(w[2][k * 4 + 3], u2h(hv.w), a2);
            a3 = FDOT2(w[3][k * 4 + 3], u2h(hv.w), a3);
        }
        // transpose-reduce: lane q ends with FULL sum of gate q
        float sel01 = q1 ? a1 : a0;
        float alt01 = q1 ? a0 : a1;
        sel01 += dpp_qperm<QP_XOR1>(alt01);
        float sel23 = q1 ? a3 : a2;
        float alt23 = q1 ? a2 : a3;
        sel23 += dpp_qperm<QP_XOR1>(alt23);
        float selq = q2 ? sel23 : sel01;
        float altq = q2 ? sel01 : sel23;
        selq += dpp_qperm<QP_XOR2>(altq);
        float xg = selq + p;

        // own-gate activation, then quad gather
        float r = fmaf(Aa, RCPF(1.0f + EXP2F(Bb * xg)), Cc);
        float gi = dpp_qperm<QP_B0>(r);
        float gf = dpp_qperm<QP_B1>(r);
        float gg = dpp_qperm<QP_B2>(r);
        float go = dpp_qperm<QP_B3>(r);
        c = fmaf(gf, c, gi * gg);
        float th = fmaf(2.0f, RCPF(1.0f + EXP2F(-2.f * L2E * c)), -1.0f);
        float h = go * th;
        if (q == 0) {
            Lstage[(s & 15) * HID + u] = h;
            _Float16 hf = (_Float16)h;
            hb[(s + 1) & 1][u] = __builtin_bit_cast(unsigned short, hf);
        }

        // chunk boundary: ensure next chunk's async copies landed (per-wave
        // queue: [possibly 1 flush store, cs+2's 2 loads] -> vmcnt(2) drains
        // everything older, i.e. chunk cs+1's copies)
        if (so == 7) {
            asm volatile("s_waitcnt vmcnt(2)" ::: "memory");
        }
        LDS_BARRIER();

        // coalesced L flush: wave w stores row s-7+w (512B) once per 8 steps
        if (so == 7) {
            int rs = s - 7 + wv_id;
            int trow = d ? (N_SENT - rs) : rs;
            float2 v2 = *(const float2*)&Lstage[(rs & 15) * HID + (l << 1)];
            *(float2*)&L[(size_t)trow * 256 + d * HID + (l << 1)] = v2;
        }
    }
    // tail: row 768 (staged at slot 0 in the final iteration, barrier done)
    if (wv_id == 0) {
        int trow = d ? (N_SENT - 768) : 768;
        float2 v2 = *(const float2*)&Lstage[(768 & 15) * HID + (l << 1)];
        *(float2*)&L[(size_t)trow * 256 + d * HID + (l << 1)] = v2;
    }
}

// scores[i][j] = (i==j) ? -1e30 : b2 + sum_k w2[k]*tanh(Ap[i][k] + Bm[j][k])
__global__ __launch_bounds__(256) void scores_k(
    const float* __restrict__ Ap,   // [769][128]
    const float* __restrict__ Bm,   // [768][128]
    const float* __restrict__ w2,
    const float* __restrict__ b2,
    float* __restrict__ out)        // [769][768]
{
    __shared__ __align__(16) float Asl[32][132];
    __shared__ __align__(16) float Bsl[32][132];
    __shared__ __align__(16) float w2s[F_DIM];
    int tid = threadIdx.x;
    int i0 = blockIdx.x * 32, j0 = blockIdx.y * 32;

    for (int e = tid; e < 1024; e += 256) {
        int r = e >> 5;
        int qq = (e & 31) << 2;
        float4 av = (i0 + r < T_SEQ)
                        ? *(const float4*)(Ap + (size_t)(i0 + r) * F_DIM + qq)
                        : make_float4(0.f, 0.f, 0.f, 0.f);
        *(float4*)&Asl[r][qq] = av;
        float4 bv = *(const float4*)(Bm + (size_t)(j0 + r) * F_DIM + qq);
        *(float4*)&Bsl[r][qq] = bv;
    }
    if (tid < 32) {
        *(float4*)&w2s[tid * 4] = *(const float4*)(w2 + tid * 4);
    }
    __syncthreads();

    int tx = tid & 15, ty = tid >> 4;
    float s[2][2] = {};
    #pragma unroll 8
    for (int k4 = 0; k4 < F_DIM; k4 += 4) {
        float4 a0 = *(const float4*)&Asl[ty * 2][k4];
        float4 a1 = *(const float4*)&Asl[ty * 2 + 1][k4];
        float4 b0 = *(const float4*)&Bsl[tx * 2][k4];
        float4 b1v = *(const float4*)&Bsl[tx * 2 + 1][k4];
        float4 wv = *(const float4*)&w2s[k4];
        float aa[2][4] = {{a0.x, a0.y, a0.z, a0.w}, {a1.x, a1.y, a1.z, a1.w}};
        float bb[2][4] = {{b0.x, b0.y, b0.z, b0.w}, {b1v.x, b1v.y, b1v.z, b1v.w}};
        float ww[4] = {wv.x, wv.y, wv.z, wv.w};
        #pragma unroll
        for (int kk = 0; kk < 4; ++kk)
            #pragma unroll
            for (int ii = 0; ii < 2; ++ii)
                #pragma unroll
                for (int jj = 0; jj < 2; ++jj)
                    s[ii][jj] = fmaf(ww[kk], tanh_f(aa[ii][kk] + bb[jj][kk]), s[ii][jj]);
    }

    float bb2 = b2[0];
    #pragma unroll
    for (int ii = 0; ii < 2; ++ii) {
        int i = i0 + ty * 2 + ii;
        if (i < T_SEQ) {
            #pragma unroll
            for (int jj = 0; jj < 2; ++jj) {
                int j = j0 + tx * 2 + jj;
                out[(size_t)i * N_SENT + j] =
                    (i == j) ? -1.0e30f : (s[ii][jj] + bb2);
            }
        }
    }
}

extern "C" void kernel_launch(void* const* d_in, const int* in_sizes, int n_in,
                              void* d_out, int out_size, void* d_ws, size_t ws_size,
                              hipStream_t stream) {
    const float* sent = (const float*)d_in[0];
    const float* root = (const float*)d_in[2];
    const float* Wih  = (const float*)d_in[3];  // (2,2,512,256)
    const float* Whh  = (const float*)d_in[4];  // (2,2,512,128)
    const float* bih  = (const float*)d_in[5];  // (2,2,512)
    const float* bhh  = (const float*)d_in[6];  // (2,2,512)
    const float* W1   = (const float*)d_in[7];  // (128,512)
    const float* b1   = (const float*)d_in[8];  // (128)
    const float* w2   = (const float*)d_in[9];  // (128)
    const float* b2   = (const float*)d_in[10]; // (1)
    float* out = (float*)d_out;
    float* ws = (float*)d_ws;

    float* x   = ws;                       // 769*256
    float* pre = x + T_SEQ * E_IN;         // 2*769*512
    float* L0  = pre + 2 * T_SEQ * G4;     // 769*256
    float* L1  = L0 + T_SEQ * 256;         // 769*256
    float* Ap  = L1 + T_SEQ * 256;         // 769*128
    float* Bm  = Ap + T_SEQ * F_DIM;       // 768*128

    build_x<<<T_SEQ, E_IN, 0, stream>>>(sent, root, x);

    dim3 b256(256);
    dim3 gpre(13, 8);
    gemm_nt<<<gpre, b256, 0, stream>>>(x, E_IN, T_SEQ, 0,
                                       Wih, E_IN, bih, bhh, pre, G4, E_IN);
    gemm_nt<<<gpre, b256, 0, stream>>>(x, E_IN, T_SEQ, 1,
                                       Wih + (size_t)G4 * E_IN, E_IN,
                                       bih + G4, bhh + G4,
                                       pre + (size_t)T_SEQ * G4, G4, E_IN);
    lstm_layer<<<2, 512, 0, stream>>>(pre, Whh, L0);

    gemm_nt<<<gpre, b256, 0, stream>>>(L0, 256, T_SEQ, 0,
                                       Wih + (size_t)2 * G4 * E_IN, 256,
                                       bih + 2 * G4, bhh + 2 * G4, pre, G4, 256);
    gemm_nt<<<gpre, b256, 0, stream>>>(L0, 256, T_SEQ, 1,
                                       Wih + (size_t)3 * G4 * E_IN, 256,
                                       bih + 3 * G4, bhh + 3 * G4,
                                       pre + (size_t)T_SEQ * G4, G4, 256);
    lstm_layer<<<2, 512, 0, stream>>>(pre, Whh + (size_t)2 * G4 * HID, L1);

    gemm_nt<<<dim3(13, 2), b256, 0, stream>>>(L1, 256, T_SEQ, 0,
                                              W1, 512, b1, nullptr, Ap, F_DIM, 256);
    gemm_nt<<<dim3(12, 2), b256, 0, stream>>>(L1, 256, N_SENT, 0,
                                              W1 + 256, 512, nullptr, nullptr, Bm, F_DIM, 256);

    scores_k<<<dim3(25, 24), b256, 0, stream>>>(Ap, Bm, w2, b2, out);
}

// Round 12
// 1055.668 us; speedup vs baseline: 1.0887x; 1.0887x over previous
//
#include <hip/hip_runtime.h>

#define T_SEQ 769
#define N_SENT 768
#define E_IN 256
#define HID 128
#define G4 512
#define F_DIM 128

typedef _Float16 f16x8 __attribute__((ext_vector_type(8)));
typedef float f32x4 __attribute__((ext_vector_type(4)));

#if __has_builtin(__builtin_amdgcn_rcpf)
#define RCPF(x) __builtin_amdgcn_rcpf(x)
#else
#define RCPF(x) (1.0f / (x))
#endif

#if __has_builtin(__builtin_amdgcn_exp2f)
#define EXP2F(x) __builtin_amdgcn_exp2f(x)
#else
#define EXP2F(x) __builtin_exp2f(x)
#endif

// LDS-only barrier: waits lgkmcnt(0) then s_barrier; global prefetch loads
// stay in flight (vmcnt not drained).
#define LDS_BARRIER() asm volatile("s_waitcnt lgkmcnt(0)\n\ts_barrier" ::: "memory")

#define L2E 1.4426950408889634f

__device__ __forceinline__ float sigm_fast(float x) {
    return RCPF(1.0f + EXP2F(-L2E * x));
}
__device__ __forceinline__ float tanh_fast(float x) {
    return fmaf(2.0f, RCPF(1.0f + EXP2F(-2.0f * L2E * x)), -1.0f);
}
__device__ __forceinline__ float tanh_f(float x) {
    return 1.0f - 2.0f / (1.0f + __expf(2.0f * x));
}

// x = concat(sentence (768x256), root (1x256))
__global__ void build_x(const float* __restrict__ sent, const float* __restrict__ root,
                        float* __restrict__ x) {
    int row = blockIdx.x;
    int c = threadIdx.x;
    x[row * E_IN + c] = (row < N_SENT) ? sent[row * E_IN + c] : root[c];
}

// C[m,n] = sum_k A[ar(m),k] * B[n,k] + b0[n] + b1[n]
__global__ __launch_bounds__(256) void gemm_nt(
    const float* __restrict__ A, int lda, int M, int revA,
    const float* __restrict__ B, int ldb,
    const float* __restrict__ b0, const float* __restrict__ b1,
    float* __restrict__ C, int ldc, int K)
{
    __shared__ __align__(16) float As[16][68];
    __shared__ __align__(16) float Bs[16][68];
    int tid = threadIdx.x;
    int tx = tid & 15, ty = tid >> 4;
    int m0 = blockIdx.x * 64, n0 = blockIdx.y * 64;
    float acc[4][4] = {};
    int lrow = tid >> 2;
    int lk = (tid & 3) << 2;

    for (int k0 = 0; k0 < K; k0 += 16) {
        int m = m0 + lrow;
        float4 av = make_float4(0.f, 0.f, 0.f, 0.f);
        if (m < M) {
            int ar = revA ? (M - 1 - m) : m;
            av = *(const float4*)(A + (size_t)ar * lda + k0 + lk);
        }
        As[lk + 0][lrow] = av.x; As[lk + 1][lrow] = av.y;
        As[lk + 2][lrow] = av.z; As[lk + 3][lrow] = av.w;
        float4 bv = *(const float4*)(B + (size_t)(n0 + lrow) * ldb + k0 + lk);
        Bs[lk + 0][lrow] = bv.x; Bs[lk + 1][lrow] = bv.y;
        Bs[lk + 2][lrow] = bv.z; Bs[lk + 3][lrow] = bv.w;
        __syncthreads();
        #pragma unroll
        for (int k = 0; k < 16; ++k) {
            float4 a4 = *(const float4*)&As[k][ty * 4];
            float4 b4 = *(const float4*)&Bs[k][tx * 4];
            float aa[4] = {a4.x, a4.y, a4.z, a4.w};
            float bb[4] = {b4.x, b4.y, b4.z, b4.w};
            #pragma unroll
            for (int i = 0; i < 4; ++i)
                #pragma unroll
                for (int j = 0; j < 4; ++j)
                    acc[i][j] = fmaf(aa[i], bb[j], acc[i][j]);
        }
        __syncthreads();
    }
    float bias[4];
    #pragma unroll
    for (int j = 0; j < 4; ++j) {
        int n = n0 + tx * 4 + j;
        bias[j] = (b0 ? b0[n] : 0.f) + (b1 ? b1[n] : 0.f);
    }
    #pragma unroll
    for (int i = 0; i < 4; ++i) {
        int m = m0 + ty * 4 + i;
        if (m < M) {
            #pragma unroll
            for (int j = 0; j < 4; ++j)
                C[(size_t)m * ldc + n0 + tx * 4 + j] = acc[i][j] + bias[j];
        }
    }
}

// One BiLSTM layer, MFMA edition. grid = 2 (dir), block = 512 (8 waves).
// Per step the 512x128 matvec runs on the MATRIX pipe: 16
// mfma_f32_16x16x32_f16 per wave (R6-R10 issued 64 v_dot2 per THREAD on the
// VALU pipe -- that issue bandwidth was the measured wall, VALUBusy ~69%).
// Mapping: wave w covers N-tiles {w, w+8, w+16, w+24} = gates i,f,g,o of
// units 16w..16w+15. h is broadcast into ALL 16 A-rows (A[m][k]=h[k]), so
// every row of C holds the result: acc[g][0] is gate g of unit 16w+(lane&15)
// in EVERY lane -- no cross-lane regroup, no second barrier.
// A-frag: 4 conflict-free ds_read_b128 of h (f16) per wave per step.
// B-frags (Whh as f16) preloaded once: 16 frags x 4 VGPR = 64 VGPRs.
// pre folded into the C-operand init (acc = {p,0,0,0}).
__global__ __launch_bounds__(512)
__attribute__((amdgpu_waves_per_eu(2, 2)))
void lstm_layer(
    const float* __restrict__ pre,
    const float* __restrict__ Whh,
    float* __restrict__ L)
{
    const int d = blockIdx.x;
    const int t = threadIdx.x;
    const int wv = t >> 6;
    const int l = t & 63;
    const int n = l & 15;       // N col = unit sub-index
    const int quad = l >> 4;    // k-group for A/B fragment layout
    const int u = wv * 16 + n;  // unit

    __shared__ __align__(16) unsigned short hb[2][HID];  // h as f16, dbuf

    // B fragments: Bf[g][kt]; B[k][nn] = Whh[d*512 + g*128 + 16w + nn][kt*32 + k]
    // lane layout: nn = lane&15, k = quad*8 + j
    f16x8 Bf[4][4];
    #pragma unroll
    for (int g = 0; g < 4; ++g) {
        const float* wr = Whh + ((size_t)d * G4 + g * HID + u) * HID;
        #pragma unroll
        for (int kt = 0; kt < 4; ++kt) {
            const float* w8 = wr + kt * 32 + quad * 8;
            float4 v0 = *(const float4*)(w8);
            float4 v1 = *(const float4*)(w8 + 4);
            f16x8 f;
            f[0] = (_Float16)v0.x; f[1] = (_Float16)v0.y;
            f[2] = (_Float16)v0.z; f[3] = (_Float16)v0.w;
            f[4] = (_Float16)v1.x; f[5] = (_Float16)v1.y;
            f[6] = (_Float16)v1.z; f[7] = (_Float16)v1.w;
            Bf[g][kt] = f;
        }
    }

    if (t < HID) { hb[0][t] = 0; hb[1][t] = 0; }

    const float* pd = pre + (size_t)d * T_SEQ * G4;
    // per-gate pre, prefetch distance 2 (all lanes load; quads duplicate)
    float p0[4], p1v[4];
    #pragma unroll
    for (int g = 0; g < 4; ++g) p0[g] = pd[g * HID + u];
    #pragma unroll
    for (int g = 0; g < 4; ++g) p1v[g] = pd[G4 + g * HID + u];
    float c = 0.f;
    __syncthreads();

    for (int s = 0; s < T_SEQ; ++s) {
        float p2[4];
        if (s + 2 < T_SEQ) {
            #pragma unroll
            for (int g = 0; g < 4; ++g)
                p2[g] = pd[(size_t)(s + 2) * G4 + g * HID + u];
        } else {
            p2[0] = p2[1] = p2[2] = p2[3] = 0.f;
        }

        // A fragments: h[kt*32 + quad*8 + j] as f16x8 (broadcast to all M rows)
        const unsigned short* hrow = &hb[s & 1][0];
        f16x8 Af[4];
        #pragma unroll
        for (int kt = 0; kt < 4; ++kt) {
            uint4 hv = *(const uint4*)(hrow + kt * 32 + quad * 8);  // 16B, conflict-free
            Af[kt] = __builtin_bit_cast(f16x8, hv);
        }

        f32x4 acc0 = {p0[0], 0.f, 0.f, 0.f};
        f32x4 acc1 = {p0[1], 0.f, 0.f, 0.f};
        f32x4 acc2 = {p0[2], 0.f, 0.f, 0.f};
        f32x4 acc3 = {p0[3], 0.f, 0.f, 0.f};
        #pragma unroll
        for (int kt = 0; kt < 4; ++kt) {
            acc0 = __builtin_amdgcn_mfma_f32_16x16x32_f16(Af[kt], Bf[0][kt], acc0, 0, 0, 0);
            acc1 = __builtin_amdgcn_mfma_f32_16x16x32_f16(Af[kt], Bf[1][kt], acc1, 0, 0, 0);
            acc2 = __builtin_amdgcn_mfma_f32_16x16x32_f16(Af[kt], Bf[2][kt], acc2, 0, 0, 0);
            acc3 = __builtin_amdgcn_mfma_f32_16x16x32_f16(Af[kt], Bf[3][kt], acc3, 0, 0, 0);
        }

        float gi = sigm_fast(acc0[0]);
        float gf = sigm_fast(acc1[0]);
        float gg = tanh_fast(acc2[0]);
        float go = sigm_fast(acc3[0]);
        c = fmaf(gf, c, gi * gg);
        float h = go * tanh_fast(c);
        if (l < 16) {
            int trow = d ? (N_SENT - s) : s;
            L[(size_t)trow * 256 + d * HID + u] = h;
            _Float16 hf = (_Float16)h;
            hb[(s + 1) & 1][u] = __builtin_bit_cast(unsigned short, hf);
        }
        #pragma unroll
        for (int g = 0; g < 4; ++g) { p0[g] = p1v[g]; p1v[g] = p2[g]; }
        LDS_BARRIER();
    }
}

// scores[i][j] = (i==j) ? -1e30 : b2 + sum_k w2[k]*tanh(Ap[i][k] + Bm[j][k])
__global__ __launch_bounds__(256) void scores_k(
    const float* __restrict__ Ap,   // [769][128]
    const float* __restrict__ Bm,   // [768][128]
    const float* __restrict__ w2,
    const float* __restrict__ b2,
    float* __restrict__ out)        // [769][768]
{
    __shared__ __align__(16) float Asl[32][132];
    __shared__ __align__(16) float Bsl[32][132];
    __shared__ __align__(16) float w2s[F_DIM];
    int tid = threadIdx.x;
    int i0 = blockIdx.x * 32, j0 = blockIdx.y * 32;

    for (int e = tid; e < 1024; e += 256) {
        int r = e >> 5;
        int qq = (e & 31) << 2;
        float4 av = (i0 + r < T_SEQ)
                        ? *(const float4*)(Ap + (size_t)(i0 + r) * F_DIM + qq)
                        : make_float4(0.f, 0.f, 0.f, 0.f);
        *(float4*)&Asl[r][qq] = av;
        float4 bv = *(const float4*)(Bm + (size_t)(j0 + r) * F_DIM + qq);
        *(float4*)&Bsl[r][qq] = bv;
    }
    if (tid < 32) {
        *(float4*)&w2s[tid * 4] = *(const float4*)(w2 + tid * 4);
    }
    __syncthreads();

    int tx = tid & 15, ty = tid >> 4;
    float s[2][2] = {};
    #pragma unroll 8
    for (int k4 = 0; k4 < F_DIM; k4 += 4) {
        float4 a0 = *(const float4*)&Asl[ty * 2][k4];
        float4 a1 = *(const float4*)&Asl[ty * 2 + 1][k4];
        float4 b0 = *(const float4*)&Bsl[tx * 2][k4];
        float4 b1v = *(const float4*)&Bsl[tx * 2 + 1][k4];
        float4 wv = *(const float4*)&w2s[k4];
        float aa[2][4] = {{a0.x, a0.y, a0.z, a0.w}, {a1.x, a1.y, a1.z, a1.w}};
        float bb[2][4] = {{b0.x, b0.y, b0.z, b0.w}, {b1v.x, b1v.y, b1v.z, b1v.w}};
        float ww[4] = {wv.x, wv.y, wv.z, wv.w};
        #pragma unroll
        for (int kk = 0; kk < 4; ++kk)
            #pragma unroll
            for (int ii = 0; ii < 2; ++ii)
                #pragma unroll
                for (int jj = 0; jj < 2; ++jj)
                    s[ii][jj] = fmaf(ww[kk], tanh_f(aa[ii][kk] + bb[jj][kk]), s[ii][jj]);
    }

    float bb2 = b2[0];
    #pragma unroll
    for (int ii = 0; ii < 2; ++ii) {
        int i = i0 + ty * 2 + ii;
        if (i < T_SEQ) {
            #pragma unroll
            for (int jj = 0; jj < 2; ++jj) {
                int j = j0 + tx * 2 + jj;
                out[(size_t)i * N_SENT + j] =
                    (i == j) ? -1.0e30f : (s[ii][jj] + bb2);
            }
        }
    }
}

extern "C" void kernel_launch(void* const* d_in, const int* in_sizes, int n_in,
                              void* d_out, int out_size, void* d_ws, size_t ws_size,
                              hipStream_t stream) {
    const float* sent = (const float*)d_in[0];
    const float* root = (const float*)d_in[2];
    const float* Wih  = (const float*)d_in[3];  // (2,2,512,256)
    const float* Whh  = (const float*)d_in[4];  // (2,2,512,128)
    const float* bih  = (const float*)d_in[5];  // (2,2,512)
    const float* bhh  = (const float*)d_in[6];  // (2,2,512)
    const float* W1   = (const float*)d_in[7];  // (128,512)
    const float* b1   = (const float*)d_in[8];  // (128)
    const float* w2   = (const float*)d_in[9];  // (128)
    const float* b2   = (const float*)d_in[10]; // (1)
    float* out = (float*)d_out;
    float* ws = (float*)d_ws;

    float* x   = ws;                       // 769*256
    float* pre = x + T_SEQ * E_IN;         // 2*769*512
    float* L0  = pre + 2 * T_SEQ * G4;     // 769*256
    float* L1  = L0 + T_SEQ * 256;         // 769*256
    float* Ap  = L1 + T_SEQ * 256;         // 769*128
    float* Bm  = Ap + T_SEQ * F_DIM;       // 768*128

    build_x<<<T_SEQ, E_IN, 0, stream>>>(sent, root, x);

    dim3 b256(256);
    dim3 gpre(13, 8);
    gemm_nt<<<gpre, b256, 0, stream>>>(x, E_IN, T_SEQ, 0,
                                       Wih, E_IN, bih, bhh, pre, G4, E_IN);
    gemm_nt<<<gpre, b256, 0, stream>>>(x, E_IN, T_SEQ, 1,
                                       Wih + (size_t)G4 * E_IN, E_IN,
                                       bih + G4, bhh + G4,
                                       pre + (size_t)T_SEQ * G4, G4, E_IN);
    lstm_layer<<<2, 512, 0, stream>>>(pre, Whh, L0);

    gemm_nt<<<gpre, b256, 0, stream>>>(L0, 256, T_SEQ, 0,
                                       Wih + (size_t)2 * G4 * E_IN, 256,
                                       bih + 2 * G4, bhh + 2 * G4, pre, G4, 256);
    gemm_nt<<<gpre, b256, 0, stream>>>(L0, 256, T_SEQ, 1,
                                       Wih + (size_t)3 * G4 * E_IN, 256,
                                       bih + 3 * G4, bhh + 3 * G4,
                                       pre + (size_t)T_SEQ * G4, G4, 256);
    lstm_layer<<<2, 512, 0, stream>>>(pre, Whh + (size_t)2 * G4 * HID, L1);

    gemm_nt<<<dim3(13, 2), b256, 0, stream>>>(L1, 256, T_SEQ, 0,
                                              W1, 512, b1, nullptr, Ap, F_DIM, 256);
    gemm_nt<<<dim3(12, 2), b256, 0, stream>>>(L1, 256, N_SENT, 0,
                                              W1 + 256, 512, nullptr, nullptr, Bm, F_DIM, 256);

    scores_k<<<dim3(25, 24), b256, 0, stream>>>(Ap, Bm, w2, b2, out);
}

// Round 13
// 1024.007 us; speedup vs baseline: 1.1224x; 1.0309x over previous
//
#include <hip/hip_runtime.h>

#define T_SEQ 769
#define N_SENT 768
#define E_IN 256
#define HID 128
#define G4 512
#define F_DIM 128

typedef _Float16 f16x8 __attribute__((ext_vector_type(8)));
typedef float f32x4 __attribute__((ext_vector_type(4)));

#if __has_builtin(__builtin_amdgcn_rcpf)
#define RCPF(x) __builtin_amdgcn_rcpf(x)
#else
#define RCPF(x) (1.0f / (x))
#endif

#if __has_builtin(__builtin_amdgcn_exp2f)
#define EXP2F(x) __builtin_amdgcn_exp2f(x)
#else
#define EXP2F(x) __builtin_exp2f(x)
#endif

// LDS-only barrier: waits lgkmcnt(0) then s_barrier; global prefetch loads
// stay in flight (vmcnt not drained).
#define LDS_BARRIER() asm volatile("s_waitcnt lgkmcnt(0)\n\ts_barrier" ::: "memory")

#define L2E 1.4426950408889634f

__device__ __forceinline__ float sigm_fast(float x) {
    return RCPF(1.0f + EXP2F(-L2E * x));
}
__device__ __forceinline__ float tanh_fast(float x) {
    return fmaf(2.0f, RCPF(1.0f + EXP2F(-2.0f * L2E * x)), -1.0f);
}
__device__ __forceinline__ float tanh_f(float x) {
    return 1.0f - 2.0f / (1.0f + __expf(2.0f * x));
}

// x = concat(sentence (768x256), root (1x256))
__global__ void build_x(const float* __restrict__ sent, const float* __restrict__ root,
                        float* __restrict__ x) {
    int row = blockIdx.x;
    int c = threadIdx.x;
    x[row * E_IN + c] = (row < N_SENT) ? sent[row * E_IN + c] : root[c];
}

// C[m,n] = sum_k A[ar(m),k] * B[n,k] + b0[n] + b1[n]
__global__ __launch_bounds__(256) void gemm_nt(
    const float* __restrict__ A, int lda, int M, int revA,
    const float* __restrict__ B, int ldb,
    const float* __restrict__ b0, const float* __restrict__ b1,
    float* __restrict__ C, int ldc, int K)
{
    __shared__ __align__(16) float As[16][68];
    __shared__ __align__(16) float Bs[16][68];
    int tid = threadIdx.x;
    int tx = tid & 15, ty = tid >> 4;
    int m0 = blockIdx.x * 64, n0 = blockIdx.y * 64;
    float acc[4][4] = {};
    int lrow = tid >> 2;
    int lk = (tid & 3) << 2;

    for (int k0 = 0; k0 < K; k0 += 16) {
        int m = m0 + lrow;
        float4 av = make_float4(0.f, 0.f, 0.f, 0.f);
        if (m < M) {
            int ar = revA ? (M - 1 - m) : m;
            av = *(const float4*)(A + (size_t)ar * lda + k0 + lk);
        }
        As[lk + 0][lrow] = av.x; As[lk + 1][lrow] = av.y;
        As[lk + 2][lrow] = av.z; As[lk + 3][lrow] = av.w;
        float4 bv = *(const float4*)(B + (size_t)(n0 + lrow) * ldb + k0 + lk);
        Bs[lk + 0][lrow] = bv.x; Bs[lk + 1][lrow] = bv.y;
        Bs[lk + 2][lrow] = bv.z; Bs[lk + 3][lrow] = bv.w;
        __syncthreads();
        #pragma unroll
        for (int k = 0; k < 16; ++k) {
            float4 a4 = *(const float4*)&As[k][ty * 4];
            float4 b4 = *(const float4*)&Bs[k][tx * 4];
            float aa[4] = {a4.x, a4.y, a4.z, a4.w};
            float bb[4] = {b4.x, b4.y, b4.z, b4.w};
            #pragma unroll
            for (int i = 0; i < 4; ++i)
                #pragma unroll
                for (int j = 0; j < 4; ++j)
                    acc[i][j] = fmaf(aa[i], bb[j], acc[i][j]);
        }
        __syncthreads();
    }
    float bias[4];
    #pragma unroll
    for (int j = 0; j < 4; ++j) {
        int n = n0 + tx * 4 + j;
        bias[j] = (b0 ? b0[n] : 0.f) + (b1 ? b1[n] : 0.f);
    }
    #pragma unroll
    for (int i = 0; i < 4; ++i) {
        int m = m0 + ty * 4 + i;
        if (m < M) {
            #pragma unroll
            for (int j = 0; j < 4; ++j)
                C[(size_t)m * ldc + n0 + tx * 4 + j] = acc[i][j] + bias[j];
        }
    }
}

// One BiLSTM layer, MFMA edition (R12 skeleton, leaner issue).
// grid = 2 (dir), block = 512 (8 waves). Wave w: gates i,f,g,o of units
// 16w..16w+15 via 16 mfma_f32_16x16x32_f16 (matrix pipe). h broadcast into
// all A rows so acc_g[0] = y[col]+p in EVERY lane. R13 changes vs R12:
//  - p loads via wave-uniform base pointer advanced once per step (scalar
//    increment; per-lane offset loop-invariant) -- was ~20 VALU/thread of
//    64-bit address math per step.
//  - depth-2 MFMA chains (kt01/kt23 + v_add merge) halve exposed matrix
//    latency vs the 4-deep chain.
//  - unroll 2: folds s&1 buffer selects and p-rotation movs.
__global__ __launch_bounds__(512)
__attribute__((amdgpu_waves_per_eu(2, 2)))
void lstm_layer(
    const float* __restrict__ pre,
    const float* __restrict__ Whh,
    float* __restrict__ L)
{
    const int d = blockIdx.x;
    const int t = threadIdx.x;
    const int wv = t >> 6;
    const int l = t & 63;
    const int n = l & 15;       // N col = unit sub-index
    const int quad = l >> 4;    // k-group for A/B fragment layout
    const int u = wv * 16 + n;  // unit

    __shared__ __align__(16) unsigned short hb[2][HID];  // h as f16, dbuf

    // B fragments: Bf[g][kt]; lane layout: nn = lane&15, k = quad*8 + j
    f16x8 Bf[4][4];
    #pragma unroll
    for (int g = 0; g < 4; ++g) {
        const float* wr = Whh + ((size_t)d * G4 + g * HID + u) * HID;
        #pragma unroll
        for (int kt = 0; kt < 4; ++kt) {
            const float* w8 = wr + kt * 32 + quad * 8;
            float4 v0 = *(const float4*)(w8);
            float4 v1 = *(const float4*)(w8 + 4);
            f16x8 f;
            f[0] = (_Float16)v0.x; f[1] = (_Float16)v0.y;
            f[2] = (_Float16)v0.z; f[3] = (_Float16)v0.w;
            f[4] = (_Float16)v1.x; f[5] = (_Float16)v1.y;
            f[6] = (_Float16)v1.z; f[7] = (_Float16)v1.w;
            Bf[g][kt] = f;
        }
    }

    if (t < HID) { hb[0][t] = 0; hb[1][t] = 0; }

    // p loads: wave-uniform rolling pointer + loop-invariant lane offset.
    const float* pp = pre + (size_t)d * T_SEQ * G4;  // points at step s+2 row
    const int po = u;                                 // + g*HID per gate
    float p0[4], p1v[4];
    #pragma unroll
    for (int g = 0; g < 4; ++g) p0[g] = pp[g * HID + po];
    pp += G4;
    #pragma unroll
    for (int g = 0; g < 4; ++g) p1v[g] = pp[g * HID + po];
    pp += G4;
    float c = 0.f;
    __syncthreads();

    #pragma unroll 2
    for (int s = 0; s < T_SEQ; ++s) {
        // A fragments first (earliest lgkm drain after the barrier)
        const unsigned short* hrow = &hb[s & 1][0];
        f16x8 Af[4];
        #pragma unroll
        for (int kt = 0; kt < 4; ++kt) {
            uint4 hv = *(const uint4*)(hrow + kt * 32 + quad * 8);  // 16B, conflict-free
            Af[kt] = __builtin_bit_cast(f16x8, hv);
        }

        // prefetch distance 2 via rolling uniform pointer (scalar increment)
        float p2[4];
        if (s + 2 < T_SEQ) {
            #pragma unroll
            for (int g = 0; g < 4; ++g) p2[g] = pp[g * HID + po];
        } else {
            p2[0] = p2[1] = p2[2] = p2[3] = 0.f;
        }
        pp += G4;

        // depth-2 MFMA chains per gate: kt01 and kt23, merged with one add
        f32x4 aA0 = {p0[0], 0.f, 0.f, 0.f}, aB0 = {0.f, 0.f, 0.f, 0.f};
        f32x4 aA1 = {p0[1], 0.f, 0.f, 0.f}, aB1 = {0.f, 0.f, 0.f, 0.f};
        f32x4 aA2 = {p0[2], 0.f, 0.f, 0.f}, aB2 = {0.f, 0.f, 0.f, 0.f};
        f32x4 aA3 = {p0[3], 0.f, 0.f, 0.f}, aB3 = {0.f, 0.f, 0.f, 0.f};
        aA0 = __builtin_amdgcn_mfma_f32_16x16x32_f16(Af[0], Bf[0][0], aA0, 0, 0, 0);
        aA1 = __builtin_amdgcn_mfma_f32_16x16x32_f16(Af[0], Bf[1][0], aA1, 0, 0, 0);
        aA2 = __builtin_amdgcn_mfma_f32_16x16x32_f16(Af[0], Bf[2][0], aA2, 0, 0, 0);
        aA3 = __builtin_amdgcn_mfma_f32_16x16x32_f16(Af[0], Bf[3][0], aA3, 0, 0, 0);
        aB0 = __builtin_amdgcn_mfma_f32_16x16x32_f16(Af[2], Bf[0][2], aB0, 0, 0, 0);
        aB1 = __builtin_amdgcn_mfma_f32_16x16x32_f16(Af[2], Bf[1][2], aB1, 0, 0, 0);
        aB2 = __builtin_amdgcn_mfma_f32_16x16x32_f16(Af[2], Bf[2][2], aB2, 0, 0, 0);
        aB3 = __builtin_amdgcn_mfma_f32_16x16x32_f16(Af[2], Bf[3][2], aB3, 0, 0, 0);
        aA0 = __builtin_amdgcn_mfma_f32_16x16x32_f16(Af[1], Bf[0][1], aA0, 0, 0, 0);
        aA1 = __builtin_amdgcn_mfma_f32_16x16x32_f16(Af[1], Bf[1][1], aA1, 0, 0, 0);
        aA2 = __builtin_amdgcn_mfma_f32_16x16x32_f16(Af[1], Bf[2][1], aA2, 0, 0, 0);
        aA3 = __builtin_amdgcn_mfma_f32_16x16x32_f16(Af[1], Bf[3][1], aA3, 0, 0, 0);
        aB0 = __builtin_amdgcn_mfma_f32_16x16x32_f16(Af[3], Bf[0][3], aB0, 0, 0, 0);
        aB1 = __builtin_amdgcn_mfma_f32_16x16x32_f16(Af[3], Bf[1][3], aB1, 0, 0, 0);
        aB2 = __builtin_amdgcn_mfma_f32_16x16x32_f16(Af[3], Bf[2][3], aB2, 0, 0, 0);
        aB3 = __builtin_amdgcn_mfma_f32_16x16x32_f16(Af[3], Bf[3][3], aB3, 0, 0, 0);

        float gi = sigm_fast(aA0[0] + aB0[0]);
        float gf = sigm_fast(aA1[0] + aB1[0]);
        float gg = tanh_fast(aA2[0] + aB2[0]);
        float go = sigm_fast(aA3[0] + aB3[0]);
        c = fmaf(gf, c, gi * gg);
        float h = go * tanh_fast(c);
        if (l < 16) {
            int trow = d ? (N_SENT - s) : s;
            L[(size_t)trow * 256 + d * HID + u] = h;
            _Float16 hf = (_Float16)h;
            hb[(s + 1) & 1][u] = __builtin_bit_cast(unsigned short, hf);
        }
        #pragma unroll
        for (int g = 0; g < 4; ++g) { p0[g] = p1v[g]; p1v[g] = p2[g]; }
        LDS_BARRIER();
    }
}

// scores[i][j] = (i==j) ? -1e30 : b2 + sum_k w2[k]*tanh(Ap[i][k] + Bm[j][k])
__global__ __launch_bounds__(256) void scores_k(
    const float* __restrict__ Ap,   // [769][128]
    const float* __restrict__ Bm,   // [768][128]
    const float* __restrict__ w2,
    const float* __restrict__ b2,
    float* __restrict__ out)        // [769][768]
{
    __shared__ __align__(16) float Asl[32][132];
    __shared__ __align__(16) float Bsl[32][132];
    __shared__ __align__(16) float w2s[F_DIM];
    int tid = threadIdx.x;
    int i0 = blockIdx.x * 32, j0 = blockIdx.y * 32;

    for (int e = tid; e < 1024; e += 256) {
        int r = e >> 5;
        int qq = (e & 31) << 2;
        float4 av = (i0 + r < T_SEQ)
                        ? *(const float4*)(Ap + (size_t)(i0 + r) * F_DIM + qq)
                        : make_float4(0.f, 0.f, 0.f, 0.f);
        *(float4*)&Asl[r][qq] = av;
        float4 bv = *(const float4*)(Bm + (size_t)(j0 + r) * F_DIM + qq);
        *(float4*)&Bsl[r][qq] = bv;
    }
    if (tid < 32) {
        *(float4*)&w2s[tid * 4] = *(const float4*)(w2 + tid * 4);
    }
    __syncthreads();

    int tx = tid & 15, ty = tid >> 4;
    float s[2][2] = {};
    #pragma unroll 8
    for (int k4 = 0; k4 < F_DIM; k4 += 4) {
        float4 a0 = *(const float4*)&Asl[ty * 2][k4];
        float4 a1 = *(const float4*)&Asl[ty * 2 + 1][k4];
        float4 b0 = *(const float4*)&Bsl[tx * 2][k4];
        float4 b1v = *(const float4*)&Bsl[tx * 2 + 1][k4];
        float4 wv = *(const float4*)&w2s[k4];
        float aa[2][4] = {{a0.x, a0.y, a0.z, a0.w}, {a1.x, a1.y, a1.z, a1.w}};
        float bb[2][4] = {{b0.x, b0.y, b0.z, b0.w}, {b1v.x, b1v.y, b1v.z, b1v.w}};
        float ww[4] = {wv.x, wv.y, wv.z, wv.w};
        #pragma unroll
        for (int kk = 0; kk < 4; ++kk)
            #pragma unroll
            for (int ii = 0; ii < 2; ++ii)
                #pragma unroll
                for (int jj = 0; jj < 2; ++jj)
                    s[ii][jj] = fmaf(ww[kk], tanh_f(aa[ii][kk] + bb[jj][kk]), s[ii][jj]);
    }

    float bb2 = b2[0];
    #pragma unroll
    for (int ii = 0; ii < 2; ++ii) {
        int i = i0 + ty * 2 + ii;
        if (i < T_SEQ) {
            #pragma unroll
            for (int jj = 0; jj < 2; ++jj) {
                int j = j0 + tx * 2 + jj;
                out[(size_t)i * N_SENT + j] =
                    (i == j) ? -1.0e30f : (s[ii][jj] + bb2);
            }
        }
    }
}

extern "C" void kernel_launch(void* const* d_in, const int* in_sizes, int n_in,
                              void* d_out, int out_size, void* d_ws, size_t ws_size,
                              hipStream_t stream) {
    const float* sent = (const float*)d_in[0];
    const float* root = (const float*)d_in[2];
    const float* Wih  = (const float*)d_in[3];  // (2,2,512,256)
    const float* Whh  = (const float*)d_in[4];  // (2,2,512,128)
    const float* bih  = (const float*)d_in[5];  // (2,2,512)
    const float* bhh  = (const float*)d_in[6];  // (2,2,512)
    const float* W1   = (const float*)d_in[7];  // (128,512)
    const float* b1   = (const float*)d_in[8];  // (128)
    const float* w2   = (const float*)d_in[9];  // (128)
    const float* b2   = (const float*)d_in[10]; // (1)
    float* out = (float*)d_out;
    float* ws = (float*)d_ws;

    float* x   = ws;                       // 769*256
    float* pre = x + T_SEQ * E_IN;         // 2*769*512
    float* L0  = pre + 2 * T_SEQ * G4;     // 769*256
    float* L1  = L0 + T_SEQ * 256;         // 769*256
    float* Ap  = L1 + T_SEQ * 256;         // 769*128
    float* Bm  = Ap + T_SEQ * F_DIM;       // 768*128

    build_x<<<T_SEQ, E_IN, 0, stream>>>(sent, root, x);

    dim3 b256(256);
    dim3 gpre(13, 8);
    gemm_nt<<<gpre, b256, 0, stream>>>(x, E_IN, T_SEQ, 0,
                                       Wih, E_IN, bih, bhh, pre, G4, E_IN);
    gemm_nt<<<gpre, b256, 0, stream>>>(x, E_IN, T_SEQ, 1,
                                       Wih + (size_t)G4 * E_IN, E_IN,
                                       bih + G4, bhh + G4,
                                       pre + (size_t)T_SEQ * G4, G4, E_IN);
    lstm_layer<<<2, 512, 0, stream>>>(pre, Whh, L0);

    gemm_nt<<<gpre, b256, 0, stream>>>(L0, 256, T_SEQ, 0,
                                       Wih + (size_t)2 * G4 * E_IN, 256,
                                       bih + 2 * G4, bhh + 2 * G4, pre, G4, 256);
    gemm_nt<<<gpre, b256, 0, stream>>>(L0, 256, T_SEQ, 1,
                                       Wih + (size_t)3 * G4 * E_IN, 256,
                                       bih + 3 * G4, bhh + 3 * G4,
                                       pre + (size_t)T_SEQ * G4, G4, 256);
    lstm_layer<<<2, 512, 0, stream>>>(pre, Whh + (size_t)2 * G4 * HID, L1);

    gemm_nt<<<dim3(13, 2), b256, 0, stream>>>(L1, 256, T_SEQ, 0,
                                              W1, 512, b1, nullptr, Ap, F_DIM, 256);
    gemm_nt<<<dim3(12, 2), b256, 0, stream>>>(L1, 256, N_SENT, 0,
                                              W1 + 256, 512, nullptr, nullptr, Bm, F_DIM, 256);

    scores_k<<<dim3(25, 24), b256, 0, stream>>>(Ap, Bm, w2, b2, out);
}